// Round 1
// baseline (1615.515 us; speedup 1.0000x reference)
//
#include <hip/hip_runtime.h>
#include <stdint.h>

#define D_MODEL 1024
#define D_FF    4096
#define NE      8
#define NTOK    8192
#define CAP     1280
#define RPE     2560           // rows per expert = 2*CAP (k=0 segment + k=1 segment)
#define RTOT    (NE*RPE)       // 20480
#define TM      128
#define TN      128
#define BK      64
#define RBLK    (NTOK/4)       // router blocks (4 tokens per block)

typedef __attribute__((ext_vector_type(8))) short s8v;   // 8 x bf16 bits (4 VGPRs)
typedef __attribute__((ext_vector_type(4))) float f4v;   // MFMA accumulator

// fp32 -> bf16 round-to-nearest-even (finite inputs only)
__device__ inline unsigned short f2bf(float f) {
    unsigned int u = __float_as_uint(f);
    u += 0x7fffu + ((u >> 16) & 1u);
    return (unsigned short)(u >> 16);
}

// async global -> LDS, 16 B per lane; LDS dest is wave-uniform base + lane*16
__device__ __forceinline__ void gload16(const unsigned short* g, unsigned short* l) {
    __builtin_amdgcn_global_load_lds(
        (const __attribute__((address_space(1))) unsigned int*)g,
        (__attribute__((address_space(3))) unsigned int*)l,
        16, 0, 0);
}

// ---------------- weight fp32 -> bf16 conversion ----------------
__global__ __launch_bounds__(256) void cvt_kernel(const float* __restrict__ src,
                                                  unsigned short* __restrict__ dst, int n4) {
    int i = blockIdx.x * blockDim.x + threadIdx.x;
    int stride = gridDim.x * blockDim.x;
    for (; i < n4; i += stride) {
        float4 v = ((const float4*)src)[i];
        union { unsigned short us[4]; uint2 u2; } cv;
        cv.us[0] = f2bf(v.x); cv.us[1] = f2bf(v.y);
        cv.us[2] = f2bf(v.z); cv.us[3] = f2bf(v.w);
        ((uint2*)dst)[i] = cv.u2;
    }
}

// ---------------- router: fp64 logits, top-2, per-block prob partials ----------------
__global__ __launch_bounds__(256) void router_kernel(const float* __restrict__ x,
                                                     const float* __restrict__ gate,
                                                     int* __restrict__ e0a, int* __restrict__ e1a,
                                                     float* __restrict__ w0a, float* __restrict__ w1a,
                                                     float* __restrict__ partial) {
    __shared__ float gs[NE * D_MODEL];   // 32 KB
    __shared__ float ps[NE];
    int tid = threadIdx.x;
    for (int i = tid; i < NE * D_MODEL; i += 256) gs[i] = gate[i];
    if (tid < NE) ps[tid] = 0.0f;
    __syncthreads();
    int wv = tid >> 6, lane = tid & 63;
    int t = blockIdx.x * 4 + wv;
    const float* xr = x + (size_t)t * D_MODEL;
    double acc[NE];
    #pragma unroll
    for (int e = 0; e < NE; e++) acc[e] = 0.0;
    #pragma unroll
    for (int j = 0; j < 16; j++) {
        int d = lane + 64 * j;
        double xv = (double)xr[d];
        #pragma unroll
        for (int e = 0; e < NE; e++) acc[e] += xv * (double)gs[e * D_MODEL + d];
    }
    #pragma unroll
    for (int e = 0; e < NE; e++) {
        #pragma unroll
        for (int off = 32; off > 0; off >>= 1) acc[e] += __shfl_xor(acc[e], off);
    }
    if (lane == 0) {
        double mx = acc[0];
        #pragma unroll
        for (int e = 1; e < NE; e++) mx = fmax(mx, acc[e]);
        double p[NE], s = 0.0;
        #pragma unroll
        for (int e = 0; e < NE; e++) { p[e] = exp(acc[e] - mx); s += p[e]; }
        float p32[NE];
        #pragma unroll
        for (int e = 0; e < NE; e++) p32[e] = (float)(p[e] / s);
        int b0 = 0;
        #pragma unroll
        for (int e = 1; e < NE; e++) if (p32[e] > p32[b0]) b0 = e;   // strict > => lowest idx on tie
        int b1 = (b0 == 0) ? 1 : 0;
        #pragma unroll
        for (int e = 0; e < NE; e++) if (e != b0 && p32[e] > p32[b1]) b1 = e;
        float denom = p32[b0] + p32[b1] + 1e-10f;
        e0a[t] = b0; e1a[t] = b1;
        w0a[t] = p32[b0] / denom;
        w1a[t] = p32[b1] / denom;
        #pragma unroll
        for (int e = 0; e < NE; e++) atomicAdd(&ps[e], p32[e]);   // LDS atomic: 32/block, cheap
    }
    __syncthreads();
    if (tid < NE) partial[blockIdx.x * NE + tid] = ps[tid];
}

// ---------------- per-expert ordered capacity scan ----------------
__global__ __launch_bounds__(512) void scan_kernel(const int* __restrict__ e0a, const int* __restrict__ e1a,
                                                   const float* __restrict__ w0a, const float* __restrict__ w1a,
                                                   int* __restrict__ tok, float* __restrict__ wl,
                                                   int* __restrict__ M, int* __restrict__ counts) {
    int e = threadIdx.x >> 6;       // 8 waves, one per expert
    int lane = threadIdx.x & 63;
    unsigned long long below = (1ull << lane) - 1ull;
    int c = 0;
    for (int base = 0; base < NTOK; base += 64) {          // k = 0
        int t = base + lane;
        bool m = (e0a[t] == e);
        unsigned long long mask = __ballot(m);
        int pos = c + __popcll(mask & below);
        if (m && pos < CAP) { tok[e * RPE + pos] = t; wl[e * RPE + pos] = w0a[t]; }
        c += __popcll(mask);
    }
    int c0 = c;
    int base0 = (c0 < CAP) ? c0 : CAP;
    c = 0;
    for (int base = 0; base < NTOK; base += 64) {          // k = 1
        int t = base + lane;
        bool m = (e1a[t] == e);
        unsigned long long mask = __ballot(m);
        int pos = c + __popcll(mask & below);
        if (m && pos < CAP) { tok[e * RPE + base0 + pos] = t; wl[e * RPE + base0 + pos] = w1a[t]; }
        c += __popcll(mask);
    }
    int c1 = c;
    if (lane == 0) {
        M[e] = base0 + ((c1 < CAP) ? c1 : CAP);
        counts[e] = c0 + c1;          // pre-capacity counts, per reference
    }
}

// ---------------- gather x rows -> zero-padded bf16 buffer ----------------
__global__ __launch_bounds__(256) void gather_kernel(const float* __restrict__ x,
                                                     const int* __restrict__ tok,
                                                     const int* __restrict__ M,
                                                     unsigned short* __restrict__ Xg) {
    int wv = threadIdx.x >> 6, lane = threadIdx.x & 63;
    int r = blockIdx.x * 4 + wv;              // 0..RTOT-1
    int e = r / RPE;
    int i = r - e * RPE;
    unsigned short* dst = Xg + (size_t)r * D_MODEL;
    if (i < M[e]) {
        int t = tok[r];
        const float4* src = (const float4*)(x + (size_t)t * D_MODEL);
        #pragma unroll
        for (int j = 0; j < 4; j++) {
            float4 v = src[lane + 64 * j];
            union { unsigned short us[4]; uint2 u2; } cv;
            cv.us[0] = f2bf(v.x); cv.us[1] = f2bf(v.y);
            cv.us[2] = f2bf(v.z); cv.us[3] = f2bf(v.w);
            *(uint2*)(dst + (size_t)(lane + 64 * j) * 4) = cv.u2;
        }
    } else {
        uint2 z; z.x = 0u; z.y = 0u;
        #pragma unroll
        for (int j = 0; j < 4; j++) *(uint2*)(dst + (size_t)(lane + 64 * j) * 4) = z;
    }
}

// ---------------- GEMM1: H = silu(Xg W1^T) * (Xg W3^T), bf16 out ----------------
// m97 structure: global_load_lds width-16 staging into LINEAR LDS (no pad),
// 2 barriers per K-step, 128x128 tile, 4 waves, dual 4x4 acc.
__global__ __launch_bounds__(256) void gemm1_kernel(const unsigned short* __restrict__ Xg,
                                                    const unsigned short* __restrict__ Wb1,
                                                    const unsigned short* __restrict__ Wb3,
                                                    const int* __restrict__ M,
                                                    unsigned short* __restrict__ H) {
    __shared__ __align__(16) unsigned short As[TM * BK];
    __shared__ __align__(16) unsigned short B1s[TN * BK];
    __shared__ __align__(16) unsigned short B3s[TN * BK];
    int bx = blockIdx.x;
    int e = bx / 640;                 // 640 = 32 n-tiles * 20 m-tiles
    int r = bx - e * 640;
    int nt = r / 20;                  // mt fastest: B-strips shared by consecutive blocks
    int mt = r - nt * 20;
    if (mt * TM >= M[e]) return;      // tile fully in zero-padded region: H never read there
    const unsigned short* Ab = Xg + ((size_t)e * RPE + (size_t)mt * TM) * D_MODEL;
    const unsigned short* B1b = Wb1 + (size_t)e * D_FF * D_MODEL + (size_t)nt * TN * D_MODEL;
    const unsigned short* B3b = Wb3 + (size_t)e * D_FF * D_MODEL + (size_t)nt * TN * D_MODEL;
    int tid = threadIdx.x;
    int lane = tid & 63, wv = tid >> 6;
    int wm = wv & 1, wn = wv >> 1;
    int quad = lane >> 4, l16 = lane & 15;
    f4v acc1[4][4], acc3[4][4];
    #pragma unroll
    for (int i = 0; i < 4; i++)
        #pragma unroll
        for (int j = 0; j < 4; j++) { acc1[i][j] = 0.0f; acc3[i][j] = 0.0f; }

    for (int kt = 0; kt < D_MODEL / BK; kt++) {
        int kof = kt * BK;
        __syncthreads();              // previous iter's LDS reads done before overwrite
        #pragma unroll
        for (int c = 0; c < 4; c++) {
            int chunk = c * 256 + tid;
            int row = chunk >> 3;           // tile row
            int col = (chunk & 7) * 8;      // elem offset within BK
            int lb = (c * 256 + wv * 64) * 8;   // wave-uniform LDS elem base (lane*16B implicit)
            gload16(Ab  + (size_t)row * D_MODEL + kof + col, As  + lb);
            gload16(B1b + (size_t)row * D_MODEL + kof + col, B1s + lb);
            gload16(B3b + (size_t)row * D_MODEL + kof + col, B3s + lb);
        }
        __syncthreads();              // vmcnt(0) drain: staged tile visible
        #pragma unroll
        for (int st = 0; st < 2; st++) {
            s8v af[4], bf1[4], bf3[4];
            #pragma unroll
            for (int i = 0; i < 4; i++)
                af[i] = *(const s8v*)(As + (wm * 64 + i * 16 + l16) * BK + st * 32 + quad * 8);
            #pragma unroll
            for (int j = 0; j < 4; j++) {
                bf1[j] = *(const s8v*)(B1s + (wn * 64 + j * 16 + l16) * BK + st * 32 + quad * 8);
                bf3[j] = *(const s8v*)(B3s + (wn * 64 + j * 16 + l16) * BK + st * 32 + quad * 8);
            }
            #pragma unroll
            for (int i = 0; i < 4; i++)
                #pragma unroll
                for (int j = 0; j < 4; j++) {
                    acc1[i][j] = __builtin_amdgcn_mfma_f32_16x16x32_bf16(af[i], bf1[j], acc1[i][j], 0, 0, 0);
                    acc3[i][j] = __builtin_amdgcn_mfma_f32_16x16x32_bf16(af[i], bf3[j], acc3[i][j], 0, 0, 0);
                }
        }
    }
    size_t rowbase = (size_t)e * RPE + (size_t)mt * TM;
    #pragma unroll
    for (int i = 0; i < 4; i++) {
        #pragma unroll
        for (int j = 0; j < 4; j++) {
            int col = nt * TN + wn * 64 + j * 16 + l16;
            #pragma unroll
            for (int rg = 0; rg < 4; rg++) {
                int row = wm * 64 + i * 16 + quad * 4 + rg;   // C/D: col=lane&15, row=quad*4+reg
                float z = acc1[i][j][rg];
                float sg = z / (1.0f + __expf(-z));           // silu
                float h = sg * acc3[i][j][rg];
                H[(rowbase + row) * (size_t)D_FF + col] = f2bf(h);
            }
        }
    }
}

// ---------------- GEMM2: OUT = H W2^T, weighted scatter-add ----------------
__global__ __launch_bounds__(256) void gemm2_kernel(const unsigned short* __restrict__ H,
                                                    const unsigned short* __restrict__ Wb2,
                                                    const int* __restrict__ tok,
                                                    const float* __restrict__ wl,
                                                    const int* __restrict__ M,
                                                    float* __restrict__ out) {
    __shared__ __align__(16) unsigned short As[TM * BK];
    __shared__ __align__(16) unsigned short Bs[TN * BK];
    __shared__ int   tok_s[TM];
    __shared__ float wl_s[TM];
    int bx = blockIdx.x;
    int e = bx / 160;                 // 160 = 20 m-tiles * 8 n-tiles
    int r = bx - e * 160;
    int mt = r >> 3;                  // nt fastest: A-tile shared by consecutive blocks
    int nt = r & 7;
    int Me = M[e];
    if (mt * TM >= Me) return;        // masked rows only: skip whole tile
    const unsigned short* Ab = H + ((size_t)e * RPE + (size_t)mt * TM) * D_FF;
    const unsigned short* Bb = Wb2 + (size_t)e * D_MODEL * D_FF + (size_t)nt * TN * D_FF;
    int tid = threadIdx.x;
    if (tid < TM) {
        tok_s[tid] = tok[e * RPE + mt * TM + tid];
        wl_s[tid]  = wl[e * RPE + mt * TM + tid];
    }
    int lane = tid & 63, wv = tid >> 6;
    int wm = wv & 1, wn = wv >> 1;
    int quad = lane >> 4, l16 = lane & 15;
    f4v acc[4][4];
    #pragma unroll
    for (int i = 0; i < 4; i++)
        #pragma unroll
        for (int j = 0; j < 4; j++) acc[i][j] = 0.0f;

    for (int kt = 0; kt < D_FF / BK; kt++) {
        int kof = kt * BK;
        __syncthreads();
        #pragma unroll
        for (int c = 0; c < 4; c++) {
            int chunk = c * 256 + tid;
            int row = chunk >> 3;
            int col = (chunk & 7) * 8;
            int lb = (c * 256 + wv * 64) * 8;
            gload16(Ab + (size_t)row * D_FF + kof + col, As + lb);
            gload16(Bb + (size_t)row * D_FF + kof + col, Bs + lb);
        }
        __syncthreads();
        #pragma unroll
        for (int st = 0; st < 2; st++) {
            s8v af[4], bf[4];
            #pragma unroll
            for (int i = 0; i < 4; i++)
                af[i] = *(const s8v*)(As + (wm * 64 + i * 16 + l16) * BK + st * 32 + quad * 8);
            #pragma unroll
            for (int j = 0; j < 4; j++)
                bf[j] = *(const s8v*)(Bs + (wn * 64 + j * 16 + l16) * BK + st * 32 + quad * 8);
            #pragma unroll
            for (int i = 0; i < 4; i++)
                #pragma unroll
                for (int j = 0; j < 4; j++)
                    acc[i][j] = __builtin_amdgcn_mfma_f32_16x16x32_bf16(af[i], bf[j], acc[i][j], 0, 0, 0);
        }
    }
    int mbase = mt * TM;
    #pragma unroll
    for (int i = 0; i < 4; i++) {
        #pragma unroll
        for (int j = 0; j < 4; j++) {
            int col = nt * TN + wn * 64 + j * 16 + l16;
            #pragma unroll
            for (int rg = 0; rg < 4; rg++) {
                int row = wm * 64 + i * 16 + quad * 4 + rg;
                if (mbase + row < Me) {
                    float v = acc[i][j][rg] * wl_s[row];
                    atomicAdd(out + (size_t)tok_s[row] * D_MODEL + col, v);
                }
            }
        }
    }
}

// ---------------- aux loss finisher: reduce per-block prob partials ----------------
__global__ __launch_bounds__(64) void aux_kernel(const int* __restrict__ counts,
                                                 const float* __restrict__ partial,
                                                 float* __restrict__ out_aux) {
    __shared__ float red[64];
    int tid = threadIdx.x;
    int e = tid & 7;            // expert
    int chunk = tid >> 3;       // 8 chunks of 256 blocks
    float s = 0.0f;
    for (int b = chunk * (RBLK / 8); b < (chunk + 1) * (RBLK / 8); b++)
        s += partial[b * NE + e];
    red[tid] = s;
    __syncthreads();
    if (tid == 0) {
        float total = 0.0f;
        for (int e2 = 0; e2 < NE; e2++) {
            float P = 0.0f;
            for (int c = 0; c < 8; c++) P += red[c * 8 + e2];
            P /= (float)NTOK;
            float f = (float)counts[e2] / (float)(NTOK * 2);
            total += f * P;
        }
        *out_aux = (float)NE * total;
    }
}

extern "C" void kernel_launch(void* const* d_in, const int* in_sizes, int n_in,
                              void* d_out, int out_size, void* d_ws, size_t ws_size,
                              hipStream_t stream) {
    (void)in_sizes; (void)n_in; (void)ws_size;
    const float* x    = (const float*)d_in[0];
    const float* gate = (const float*)d_in[1];
    const float* w1   = (const float*)d_in[2];
    const float* w2   = (const float*)d_in[3];   // dict order: x, gate_w, w1, w2, w3
    const float* w3   = (const float*)d_in[4];
    float* out = (float*)d_out;

    const size_t WB = (size_t)NE * D_FF * D_MODEL * 2;   // 64 MB per weight in bf16
    char* p = (char*)d_ws;
    unsigned short* Wb1 = (unsigned short*)p;  p += WB;
    unsigned short* Wb3 = (unsigned short*)p;  p += WB;
    unsigned short* Wb2 = (unsigned short*)p;  p += WB;
    unsigned short* Xg  = (unsigned short*)p;  p += (size_t)RTOT * D_MODEL * 2;
    unsigned short* H   = (unsigned short*)p;  p += (size_t)RTOT * D_FF * 2;
    int*   e0a = (int*)p;    p += NTOK * 4;
    int*   e1a = (int*)p;    p += NTOK * 4;
    float* w0a = (float*)p;  p += NTOK * 4;
    float* w1a = (float*)p;  p += NTOK * 4;
    int*   tok = (int*)p;    p += RTOT * 4;
    float* wl  = (float*)p;  p += RTOT * 4;
    int*   M   = (int*)p;    p += 64;
    int*   counts = (int*)p; p += 64;
    float* partial = (float*)p; p += RBLK * NE * 4;   // 2048*8 floats

    hipMemsetAsync(d_out, 0, (size_t)out_size * 4, stream);

    int n4 = NE * D_FF * D_MODEL / 4;
    cvt_kernel<<<2048, 256, 0, stream>>>(w1, Wb1, n4);
    cvt_kernel<<<2048, 256, 0, stream>>>(w3, Wb3, n4);
    cvt_kernel<<<2048, 256, 0, stream>>>(w2, Wb2, n4);

    router_kernel<<<RBLK, 256, 0, stream>>>(x, gate, e0a, e1a, w0a, w1a, partial);
    scan_kernel<<<1, 512, 0, stream>>>(e0a, e1a, w0a, w1a, tok, wl, M, counts);
    gather_kernel<<<RTOT / 4, 256, 0, stream>>>(x, tok, M, Xg);

    gemm1_kernel<<<NE * 20 * 32, 256, 0, stream>>>(Xg, Wb1, Wb3, M, H);
    gemm2_kernel<<<NE * 20 * 8, 256, 0, stream>>>(H, Wb2, tok, wl, M, out);

    aux_kernel<<<1, 64, 0, stream>>>(counts, partial, out + (size_t)NTOK * D_MODEL);
}

// Round 2
// 1123.872 us; speedup vs baseline: 1.4375x; 1.4375x over previous
//
#include <hip/hip_runtime.h>
#include <stdint.h>

#define D_MODEL 1024
#define D_FF    4096
#define NE      8
#define NTOK    8192
#define CAP     1280
#define RPE     2560           // rows per expert = 2*CAP (k=0 segment + k=1 segment)
#define RTOT    (NE*RPE)       // 20480
#define TM      128
#define TN1     64             // gemm1 n-tile (wave tile 64x32, dual acc = 64 AGPR)
#define TN      128            // gemm2 n-tile
#define BK      64
#define RBLK    (NTOK/4)       // router blocks (4 tokens per block)

typedef __attribute__((ext_vector_type(8))) short s8v;   // 8 x bf16 bits (4 VGPRs)
typedef __attribute__((ext_vector_type(4))) float f4v;   // MFMA accumulator

// fp32 -> bf16 round-to-nearest-even (finite inputs only)
__device__ inline unsigned short f2bf(float f) {
    unsigned int u = __float_as_uint(f);
    u += 0x7fffu + ((u >> 16) & 1u);
    return (unsigned short)(u >> 16);
}

// async global -> LDS, 16 B per lane; LDS dest is wave-uniform base + lane*16
__device__ __forceinline__ void gload16(const unsigned short* g, unsigned short* l) {
    __builtin_amdgcn_global_load_lds(
        (const __attribute__((address_space(1))) unsigned int*)g,
        (__attribute__((address_space(3))) unsigned int*)l,
        16, 0, 0);
}

// ---------------- weight fp32 -> bf16 conversion ----------------
__global__ __launch_bounds__(256) void cvt_kernel(const float* __restrict__ src,
                                                  unsigned short* __restrict__ dst, int n4) {
    int i = blockIdx.x * blockDim.x + threadIdx.x;
    int stride = gridDim.x * blockDim.x;
    for (; i < n4; i += stride) {
        float4 v = ((const float4*)src)[i];
        union { unsigned short us[4]; uint2 u2; } cv;
        cv.us[0] = f2bf(v.x); cv.us[1] = f2bf(v.y);
        cv.us[2] = f2bf(v.z); cv.us[3] = f2bf(v.w);
        ((uint2*)dst)[i] = cv.u2;
    }
}

// ---------------- router: fp64 logits, top-2, per-block prob partials ----------------
__global__ __launch_bounds__(256) void router_kernel(const float* __restrict__ x,
                                                     const float* __restrict__ gate,
                                                     int* __restrict__ e0a, int* __restrict__ e1a,
                                                     float* __restrict__ w0a, float* __restrict__ w1a,
                                                     float* __restrict__ partial) {
    __shared__ float gs[NE * D_MODEL];   // 32 KB
    __shared__ float ps[NE];
    int tid = threadIdx.x;
    for (int i = tid; i < NE * D_MODEL; i += 256) gs[i] = gate[i];
    if (tid < NE) ps[tid] = 0.0f;
    __syncthreads();
    int wv = tid >> 6, lane = tid & 63;
    int t = blockIdx.x * 4 + wv;
    const float* xr = x + (size_t)t * D_MODEL;
    double acc[NE];
    #pragma unroll
    for (int e = 0; e < NE; e++) acc[e] = 0.0;
    #pragma unroll
    for (int j = 0; j < 16; j++) {
        int d = lane + 64 * j;
        double xv = (double)xr[d];
        #pragma unroll
        for (int e = 0; e < NE; e++) acc[e] += xv * (double)gs[e * D_MODEL + d];
    }
    #pragma unroll
    for (int e = 0; e < NE; e++) {
        #pragma unroll
        for (int off = 32; off > 0; off >>= 1) acc[e] += __shfl_xor(acc[e], off);
    }
    if (lane == 0) {
        double mx = acc[0];
        #pragma unroll
        for (int e = 1; e < NE; e++) mx = fmax(mx, acc[e]);
        double p[NE], s = 0.0;
        #pragma unroll
        for (int e = 0; e < NE; e++) { p[e] = exp(acc[e] - mx); s += p[e]; }
        float p32[NE];
        #pragma unroll
        for (int e = 0; e < NE; e++) p32[e] = (float)(p[e] / s);
        int b0 = 0;
        #pragma unroll
        for (int e = 1; e < NE; e++) if (p32[e] > p32[b0]) b0 = e;   // strict > => lowest idx on tie
        int b1 = (b0 == 0) ? 1 : 0;
        #pragma unroll
        for (int e = 0; e < NE; e++) if (e != b0 && p32[e] > p32[b1]) b1 = e;
        float denom = p32[b0] + p32[b1] + 1e-10f;
        e0a[t] = b0; e1a[t] = b1;
        w0a[t] = p32[b0] / denom;
        w1a[t] = p32[b1] / denom;
        #pragma unroll
        for (int e = 0; e < NE; e++) atomicAdd(&ps[e], p32[e]);   // LDS atomic: 32/block, cheap
    }
    __syncthreads();
    if (tid < NE) partial[blockIdx.x * NE + tid] = ps[tid];
}

// ---------------- per-expert ordered capacity scan ----------------
__global__ __launch_bounds__(512) void scan_kernel(const int* __restrict__ e0a, const int* __restrict__ e1a,
                                                   const float* __restrict__ w0a, const float* __restrict__ w1a,
                                                   int* __restrict__ tok, float* __restrict__ wl,
                                                   int* __restrict__ M, int* __restrict__ counts) {
    int e = threadIdx.x >> 6;       // 8 waves, one per expert
    int lane = threadIdx.x & 63;
    unsigned long long below = (1ull << lane) - 1ull;
    int c = 0;
    for (int base = 0; base < NTOK; base += 64) {          // k = 0
        int t = base + lane;
        bool m = (e0a[t] == e);
        unsigned long long mask = __ballot(m);
        int pos = c + __popcll(mask & below);
        if (m && pos < CAP) { tok[e * RPE + pos] = t; wl[e * RPE + pos] = w0a[t]; }
        c += __popcll(mask);
    }
    int c0 = c;
    int base0 = (c0 < CAP) ? c0 : CAP;
    c = 0;
    for (int base = 0; base < NTOK; base += 64) {          // k = 1
        int t = base + lane;
        bool m = (e1a[t] == e);
        unsigned long long mask = __ballot(m);
        int pos = c + __popcll(mask & below);
        if (m && pos < CAP) { tok[e * RPE + base0 + pos] = t; wl[e * RPE + base0 + pos] = w1a[t]; }
        c += __popcll(mask);
    }
    int c1 = c;
    if (lane == 0) {
        M[e] = base0 + ((c1 < CAP) ? c1 : CAP);
        counts[e] = c0 + c1;          // pre-capacity counts, per reference
    }
}

// ---------------- gather x rows -> zero-padded bf16 buffer ----------------
__global__ __launch_bounds__(256) void gather_kernel(const float* __restrict__ x,
                                                     const int* __restrict__ tok,
                                                     const int* __restrict__ M,
                                                     unsigned short* __restrict__ Xg) {
    int wv = threadIdx.x >> 6, lane = threadIdx.x & 63;
    int r = blockIdx.x * 4 + wv;              // 0..RTOT-1
    int e = r / RPE;
    int i = r - e * RPE;
    unsigned short* dst = Xg + (size_t)r * D_MODEL;
    if (i < M[e]) {
        int t = tok[r];
        const float4* src = (const float4*)(x + (size_t)t * D_MODEL);
        #pragma unroll
        for (int j = 0; j < 4; j++) {
            float4 v = src[lane + 64 * j];
            union { unsigned short us[4]; uint2 u2; } cv;
            cv.us[0] = f2bf(v.x); cv.us[1] = f2bf(v.y);
            cv.us[2] = f2bf(v.z); cv.us[3] = f2bf(v.w);
            *(uint2*)(dst + (size_t)(lane + 64 * j) * 4) = cv.u2;
        }
    } else {
        uint2 z; z.x = 0u; z.y = 0u;
        #pragma unroll
        for (int j = 0; j < 4; j++) *(uint2*)(dst + (size_t)(lane + 64 * j) * 4) = z;
    }
}

// ---------------- GEMM1: H = silu(Xg W1^T) * (Xg W3^T), bf16 out ----------------
// 128x64 tile, 4 waves (2x2), wave tile 64x32, dual acc = 64 AGPR total.
// global_load_lds staging into linear LDS with XOR chunk swizzle applied to the
// GLOBAL source (rule 21: both-sides-or-neither); reads XOR the same pattern.
// __launch_bounds__(256,2): cap regs at 256 -> 2 waves/SIMD (round-1 was 1/SIMD).
__global__ __launch_bounds__(256, 2) void gemm1_kernel(const unsigned short* __restrict__ Xg,
                                                       const unsigned short* __restrict__ Wb1,
                                                       const unsigned short* __restrict__ Wb3,
                                                       const int* __restrict__ M,
                                                       unsigned short* __restrict__ H) {
    __shared__ __align__(16) unsigned short As[TM * BK];    // 16 KB
    __shared__ __align__(16) unsigned short B1s[TN1 * BK];  // 8 KB
    __shared__ __align__(16) unsigned short B3s[TN1 * BK];  // 8 KB
    int bx = blockIdx.x;
    int e = bx / 1280;                // 1280 = 64 n-tiles * 20 m-tiles
    int r = bx - e * 1280;
    int nt = r / 20;                  // mt fastest: B-strips shared by consecutive blocks
    int mt = r - nt * 20;
    if (mt * TM >= M[e]) return;      // tile fully in zero-padded region: H never read there
    const unsigned short* Ab  = Xg  + ((size_t)e * RPE + (size_t)mt * TM) * D_MODEL;
    const unsigned short* B1b = Wb1 + (size_t)e * D_FF * D_MODEL + (size_t)nt * TN1 * D_MODEL;
    const unsigned short* B3b = Wb3 + (size_t)e * D_FF * D_MODEL + (size_t)nt * TN1 * D_MODEL;
    int tid = threadIdx.x;
    int lane = tid & 63, wv = tid >> 6;
    int wm = wv & 1, wn = wv >> 1;    // 2x2 wave grid
    int quad = lane >> 4, l16 = lane & 15;
    f4v acc1[4][2], acc3[4][2];
    #pragma unroll
    for (int i = 0; i < 4; i++)
        #pragma unroll
        for (int j = 0; j < 2; j++) { acc1[i][j] = 0.0f; acc3[i][j] = 0.0f; }

    for (int kt = 0; kt < D_MODEL / BK; kt++) {
        int kof = kt * BK;
        __syncthreads();              // previous iter's LDS reads done before overwrite
        #pragma unroll
        for (int c = 0; c < 4; c++) { // A tile: 128 rows x 8 chunks = 1024 chunks
            int chunk = c * 256 + tid;
            int row = chunk >> 3;
            int ch  = chunk & 7;
            int gcol = (ch ^ (row & 7)) * 8;          // inverse swizzle on global src
            int lb = (c * 256 + wv * 64) * 8;         // wave-uniform LDS elem base
            gload16(Ab + (size_t)row * D_MODEL + kof + gcol, As + lb);
        }
        #pragma unroll
        for (int c = 0; c < 2; c++) { // B tiles: 64 rows x 8 chunks = 512 chunks each
            int chunk = c * 256 + tid;
            int row = chunk >> 3;
            int ch  = chunk & 7;
            int gcol = (ch ^ (row & 7)) * 8;
            int lb = (c * 256 + wv * 64) * 8;
            gload16(B1b + (size_t)row * D_MODEL + kof + gcol, B1s + lb);
            gload16(B3b + (size_t)row * D_MODEL + kof + gcol, B3s + lb);
        }
        __syncthreads();              // vmcnt(0) drain: staged tile visible
        #pragma unroll
        for (int st = 0; st < 2; st++) {
            s8v af[4], bf1[2], bf3[2];
            int cbase = st * 32 + quad * 8;           // element col, multiple of 8
            #pragma unroll
            for (int i = 0; i < 4; i++) {
                int row = wm * 64 + i * 16 + l16;
                af[i] = *(const s8v*)(As + row * BK + (cbase ^ ((row & 7) << 3)));
            }
            #pragma unroll
            for (int j = 0; j < 2; j++) {
                int row = wn * 32 + j * 16 + l16;
                bf1[j] = *(const s8v*)(B1s + row * BK + (cbase ^ ((row & 7) << 3)));
                bf3[j] = *(const s8v*)(B3s + row * BK + (cbase ^ ((row & 7) << 3)));
            }
            #pragma unroll
            for (int i = 0; i < 4; i++)
                #pragma unroll
                for (int j = 0; j < 2; j++) {
                    acc1[i][j] = __builtin_amdgcn_mfma_f32_16x16x32_bf16(af[i], bf1[j], acc1[i][j], 0, 0, 0);
                    acc3[i][j] = __builtin_amdgcn_mfma_f32_16x16x32_bf16(af[i], bf3[j], acc3[i][j], 0, 0, 0);
                }
        }
    }
    size_t rowbase = (size_t)e * RPE + (size_t)mt * TM;
    #pragma unroll
    for (int i = 0; i < 4; i++) {
        #pragma unroll
        for (int j = 0; j < 2; j++) {
            int col = nt * TN1 + wn * 32 + j * 16 + l16;
            #pragma unroll
            for (int rg = 0; rg < 4; rg++) {
                int row = wm * 64 + i * 16 + quad * 4 + rg;   // C/D: col=lane&15, row=quad*4+reg
                float z = acc1[i][j][rg];
                float sg = z / (1.0f + __expf(-z));           // silu
                float h = sg * acc3[i][j][rg];
                H[(rowbase + row) * (size_t)D_FF + col] = f2bf(h);
            }
        }
    }
}

// ---------------- GEMM2: OUT = H W2^T, weighted scatter-add ----------------
__global__ __launch_bounds__(256, 2) void gemm2_kernel(const unsigned short* __restrict__ H,
                                                       const unsigned short* __restrict__ Wb2,
                                                       const int* __restrict__ tok,
                                                       const float* __restrict__ wl,
                                                       const int* __restrict__ M,
                                                       float* __restrict__ out) {
    __shared__ __align__(16) unsigned short As[TM * BK];
    __shared__ __align__(16) unsigned short Bs[TN * BK];
    __shared__ int   tok_s[TM];
    __shared__ float wl_s[TM];
    int bx = blockIdx.x;
    int e = bx / 160;                 // 160 = 20 m-tiles * 8 n-tiles
    int r = bx - e * 160;
    int mt = r >> 3;                  // nt fastest: A-tile shared by consecutive blocks
    int nt = r & 7;
    int Me = M[e];
    if (mt * TM >= Me) return;        // masked rows only: skip whole tile
    const unsigned short* Ab = H + ((size_t)e * RPE + (size_t)mt * TM) * D_FF;
    const unsigned short* Bb = Wb2 + (size_t)e * D_MODEL * D_FF + (size_t)nt * TN * D_FF;
    int tid = threadIdx.x;
    if (tid < TM) {
        tok_s[tid] = tok[e * RPE + mt * TM + tid];
        wl_s[tid]  = wl[e * RPE + mt * TM + tid];
    }
    int lane = tid & 63, wv = tid >> 6;
    int wm = wv & 1, wn = wv >> 1;
    int quad = lane >> 4, l16 = lane & 15;
    f4v acc[4][4];
    #pragma unroll
    for (int i = 0; i < 4; i++)
        #pragma unroll
        for (int j = 0; j < 4; j++) acc[i][j] = 0.0f;

    for (int kt = 0; kt < D_FF / BK; kt++) {
        int kof = kt * BK;
        __syncthreads();
        #pragma unroll
        for (int c = 0; c < 4; c++) {
            int chunk = c * 256 + tid;
            int row = chunk >> 3;
            int ch  = chunk & 7;
            int gcol = (ch ^ (row & 7)) * 8;
            int lb = (c * 256 + wv * 64) * 8;
            gload16(Ab + (size_t)row * D_FF + kof + gcol, As + lb);
            gload16(Bb + (size_t)row * D_FF + kof + gcol, Bs + lb);
        }
        __syncthreads();
        #pragma unroll
        for (int st = 0; st < 2; st++) {
            s8v af[4], bf[4];
            int cbase = st * 32 + quad * 8;
            #pragma unroll
            for (int i = 0; i < 4; i++) {
                int row = wm * 64 + i * 16 + l16;
                af[i] = *(const s8v*)(As + row * BK + (cbase ^ ((row & 7) << 3)));
            }
            #pragma unroll
            for (int j = 0; j < 4; j++) {
                int row = wn * 64 + j * 16 + l16;
                bf[j] = *(const s8v*)(Bs + row * BK + (cbase ^ ((row & 7) << 3)));
            }
            #pragma unroll
            for (int i = 0; i < 4; i++)
                #pragma unroll
                for (int j = 0; j < 4; j++)
                    acc[i][j] = __builtin_amdgcn_mfma_f32_16x16x32_bf16(af[i], bf[j], acc[i][j], 0, 0, 0);
        }
    }
    int mbase = mt * TM;
    #pragma unroll
    for (int i = 0; i < 4; i++) {
        #pragma unroll
        for (int j = 0; j < 4; j++) {
            int col = nt * TN + wn * 64 + j * 16 + l16;
            #pragma unroll
            for (int rg = 0; rg < 4; rg++) {
                int row = wm * 64 + i * 16 + quad * 4 + rg;
                if (mbase + row < Me) {
                    float v = acc[i][j][rg] * wl_s[row];
                    atomicAdd(out + (size_t)tok_s[row] * D_MODEL + col, v);
                }
            }
        }
    }
}

// ---------------- aux loss finisher: reduce per-block prob partials ----------------
__global__ __launch_bounds__(64) void aux_kernel(const int* __restrict__ counts,
                                                 const float* __restrict__ partial,
                                                 float* __restrict__ out_aux) {
    __shared__ float red[64];
    int tid = threadIdx.x;
    int e = tid & 7;            // expert
    int chunk = tid >> 3;       // 8 chunks of 256 blocks
    float s = 0.0f;
    for (int b = chunk * (RBLK / 8); b < (chunk + 1) * (RBLK / 8); b++)
        s += partial[b * NE + e];
    red[tid] = s;
    __syncthreads();
    if (tid == 0) {
        float total = 0.0f;
        for (int e2 = 0; e2 < NE; e2++) {
            float P = 0.0f;
            for (int c = 0; c < 8; c++) P += red[c * 8 + e2];
            P /= (float)NTOK;
            float f = (float)counts[e2] / (float)(NTOK * 2);
            total += f * P;
        }
        *out_aux = (float)NE * total;
    }
}

extern "C" void kernel_launch(void* const* d_in, const int* in_sizes, int n_in,
                              void* d_out, int out_size, void* d_ws, size_t ws_size,
                              hipStream_t stream) {
    (void)in_sizes; (void)n_in; (void)ws_size;
    const float* x    = (const float*)d_in[0];
    const float* gate = (const float*)d_in[1];
    const float* w1   = (const float*)d_in[2];
    const float* w2   = (const float*)d_in[3];   // dict order: x, gate_w, w1, w2, w3
    const float* w3   = (const float*)d_in[4];
    float* out = (float*)d_out;

    const size_t WB = (size_t)NE * D_FF * D_MODEL * 2;   // 64 MB per weight in bf16
    char* p = (char*)d_ws;
    unsigned short* Wb1 = (unsigned short*)p;  p += WB;
    unsigned short* Wb3 = (unsigned short*)p;  p += WB;
    unsigned short* Wb2 = (unsigned short*)p;  p += WB;
    unsigned short* Xg  = (unsigned short*)p;  p += (size_t)RTOT * D_MODEL * 2;
    unsigned short* H   = (unsigned short*)p;  p += (size_t)RTOT * D_FF * 2;
    int*   e0a = (int*)p;    p += NTOK * 4;
    int*   e1a = (int*)p;    p += NTOK * 4;
    float* w0a = (float*)p;  p += NTOK * 4;
    float* w1a = (float*)p;  p += NTOK * 4;
    int*   tok = (int*)p;    p += RTOT * 4;
    float* wl  = (float*)p;  p += RTOT * 4;
    int*   M   = (int*)p;    p += 64;
    int*   counts = (int*)p; p += 64;
    float* partial = (float*)p; p += RBLK * NE * 4;   // 2048*8 floats

    hipMemsetAsync(d_out, 0, (size_t)out_size * 4, stream);

    int n4 = NE * D_FF * D_MODEL / 4;
    cvt_kernel<<<2048, 256, 0, stream>>>(w1, Wb1, n4);
    cvt_kernel<<<2048, 256, 0, stream>>>(w3, Wb3, n4);
    cvt_kernel<<<2048, 256, 0, stream>>>(w2, Wb2, n4);

    router_kernel<<<RBLK, 256, 0, stream>>>(x, gate, e0a, e1a, w0a, w1a, partial);
    scan_kernel<<<1, 512, 0, stream>>>(e0a, e1a, w0a, w1a, tok, wl, M, counts);
    gather_kernel<<<RTOT / 4, 256, 0, stream>>>(x, tok, M, Xg);

    gemm1_kernel<<<NE * 20 * 64, 256, 0, stream>>>(Xg, Wb1, Wb3, M, H);
    gemm2_kernel<<<NE * 20 * 8, 256, 0, stream>>>(H, Wb2, tok, wl, M, out);

    aux_kernel<<<1, 64, 0, stream>>>(counts, partial, out + (size_t)NTOK * D_MODEL);
}

// Round 3
// 1062.682 us; speedup vs baseline: 1.5202x; 1.0576x over previous
//
#include <hip/hip_runtime.h>
#include <stdint.h>

#define D_MODEL 1024
#define D_FF    4096
#define NE      8
#define NTOK    8192
#define CAP     1280
#define RPE     2560           // rows per expert = 2*CAP (k=0 segment + k=1 segment)
#define RTOT    (NE*RPE)       // 20480
#define TM      128
#define TN1     64             // gemm1 n-tile (wave tile 64x32, dual acc = 64 AGPR)
#define TN      128            // gemm2 n-tile
#define BK      64
#define RBLK    (NTOK/4)       // router blocks (4 tokens per block)

typedef __attribute__((ext_vector_type(8))) short s8v;   // 8 x bf16 bits (4 VGPRs)
typedef __attribute__((ext_vector_type(4))) float f4v;   // MFMA accumulator

// fp32 -> bf16 round-to-nearest-even (finite inputs only)
__device__ inline unsigned short f2bf(float f) {
    unsigned int u = __float_as_uint(f);
    u += 0x7fffu + ((u >> 16) & 1u);
    return (unsigned short)(u >> 16);
}

// async global -> LDS, 16 B per lane; LDS dest is wave-uniform base + lane*16
__device__ __forceinline__ void gload16(const unsigned short* g, unsigned short* l) {
    __builtin_amdgcn_global_load_lds(
        (const __attribute__((address_space(1))) unsigned int*)g,
        (__attribute__((address_space(3))) unsigned int*)l,
        16, 0, 0);
}

// ---------------- weight fp32 -> bf16 conversion ----------------
__global__ __launch_bounds__(256) void cvt_kernel(const float* __restrict__ src,
                                                  unsigned short* __restrict__ dst, int n4) {
    int i = blockIdx.x * blockDim.x + threadIdx.x;
    int stride = gridDim.x * blockDim.x;
    for (; i < n4; i += stride) {
        float4 v = ((const float4*)src)[i];
        union { unsigned short us[4]; uint2 u2; } cv;
        cv.us[0] = f2bf(v.x); cv.us[1] = f2bf(v.y);
        cv.us[2] = f2bf(v.z); cv.us[3] = f2bf(v.w);
        ((uint2*)dst)[i] = cv.u2;
    }
}

// ---------------- router: fp64 logits, top-2, per-block prob partials ----------------
__global__ __launch_bounds__(256) void router_kernel(const float* __restrict__ x,
                                                     const float* __restrict__ gate,
                                                     int* __restrict__ e0a, int* __restrict__ e1a,
                                                     float* __restrict__ w0a, float* __restrict__ w1a,
                                                     float* __restrict__ partial) {
    __shared__ float gs[NE * D_MODEL];   // 32 KB
    __shared__ float ps[NE];
    int tid = threadIdx.x;
    for (int i = tid; i < NE * D_MODEL; i += 256) gs[i] = gate[i];
    if (tid < NE) ps[tid] = 0.0f;
    __syncthreads();
    int wv = tid >> 6, lane = tid & 63;
    int t = blockIdx.x * 4 + wv;
    const float* xr = x + (size_t)t * D_MODEL;
    double acc[NE];
    #pragma unroll
    for (int e = 0; e < NE; e++) acc[e] = 0.0;
    #pragma unroll
    for (int j = 0; j < 16; j++) {
        int d = lane + 64 * j;
        double xv = (double)xr[d];
        #pragma unroll
        for (int e = 0; e < NE; e++) acc[e] += xv * (double)gs[e * D_MODEL + d];
    }
    #pragma unroll
    for (int e = 0; e < NE; e++) {
        #pragma unroll
        for (int off = 32; off > 0; off >>= 1) acc[e] += __shfl_xor(acc[e], off);
    }
    if (lane == 0) {
        double mx = acc[0];
        #pragma unroll
        for (int e = 1; e < NE; e++) mx = fmax(mx, acc[e]);
        double p[NE], s = 0.0;
        #pragma unroll
        for (int e = 0; e < NE; e++) { p[e] = exp(acc[e] - mx); s += p[e]; }
        float p32[NE];
        #pragma unroll
        for (int e = 0; e < NE; e++) p32[e] = (float)(p[e] / s);
        int b0 = 0;
        #pragma unroll
        for (int e = 1; e < NE; e++) if (p32[e] > p32[b0]) b0 = e;   // strict > => lowest idx on tie
        int b1 = (b0 == 0) ? 1 : 0;
        #pragma unroll
        for (int e = 0; e < NE; e++) if (e != b0 && p32[e] > p32[b1]) b1 = e;
        float denom = p32[b0] + p32[b1] + 1e-10f;
        e0a[t] = b0; e1a[t] = b1;
        w0a[t] = p32[b0] / denom;
        w1a[t] = p32[b1] / denom;
        #pragma unroll
        for (int e = 0; e < NE; e++) atomicAdd(&ps[e], p32[e]);   // LDS atomic: 32/block, cheap
    }
    __syncthreads();
    if (tid < NE) partial[blockIdx.x * NE + tid] = ps[tid];
}

// ---------------- per-expert ordered capacity scan (+ inverse maps) ----------------
__global__ __launch_bounds__(512) void scan_kernel(const int* __restrict__ e0a, const int* __restrict__ e1a,
                                                   int* __restrict__ tok,
                                                   int* __restrict__ inv0, int* __restrict__ inv1,
                                                   int* __restrict__ M, int* __restrict__ counts) {
    int e = threadIdx.x >> 6;       // 8 waves, one per expert
    int lane = threadIdx.x & 63;
    unsigned long long below = (1ull << lane) - 1ull;
    int c = 0;
    for (int base = 0; base < NTOK; base += 64) {          // k = 0
        int t = base + lane;
        bool m = (e0a[t] == e);
        unsigned long long mask = __ballot(m);
        int pos = c + __popcll(mask & below);
        if (m) {
            if (pos < CAP) { tok[e * RPE + pos] = t; inv0[t] = e * RPE + pos; }
            else inv0[t] = -1;
        }
        c += __popcll(mask);
    }
    int c0 = c;
    int base0 = (c0 < CAP) ? c0 : CAP;
    c = 0;
    for (int base = 0; base < NTOK; base += 64) {          // k = 1
        int t = base + lane;
        bool m = (e1a[t] == e);
        unsigned long long mask = __ballot(m);
        int pos = c + __popcll(mask & below);
        if (m) {
            if (pos < CAP) { tok[e * RPE + base0 + pos] = t; inv1[t] = e * RPE + base0 + pos; }
            else inv1[t] = -1;
        }
        c += __popcll(mask);
    }
    int c1 = c;
    if (lane == 0) {
        M[e] = base0 + ((c1 < CAP) ? c1 : CAP);
        counts[e] = c0 + c1;          // pre-capacity counts, per reference
    }
}

// ---------------- gather x rows -> zero-padded bf16 buffer ----------------
__global__ __launch_bounds__(256) void gather_kernel(const float* __restrict__ x,
                                                     const int* __restrict__ tok,
                                                     const int* __restrict__ M,
                                                     unsigned short* __restrict__ Xg) {
    int wv = threadIdx.x >> 6, lane = threadIdx.x & 63;
    int r = blockIdx.x * 4 + wv;              // 0..RTOT-1
    int e = r / RPE;
    int i = r - e * RPE;
    unsigned short* dst = Xg + (size_t)r * D_MODEL;
    if (i < M[e]) {
        int t = tok[r];
        const float4* src = (const float4*)(x + (size_t)t * D_MODEL);
        #pragma unroll
        for (int j = 0; j < 4; j++) {
            float4 v = src[lane + 64 * j];
            union { unsigned short us[4]; uint2 u2; } cv;
            cv.us[0] = f2bf(v.x); cv.us[1] = f2bf(v.y);
            cv.us[2] = f2bf(v.z); cv.us[3] = f2bf(v.w);
            *(uint2*)(dst + (size_t)(lane + 64 * j) * 4) = cv.u2;
        }
    } else {
        uint2 z; z.x = 0u; z.y = 0u;
        #pragma unroll
        for (int j = 0; j < 4; j++) *(uint2*)(dst + (size_t)(lane + 64 * j) * 4) = z;
    }
}

// ---------------- GEMM1: H = silu(Xg W1^T) * (Xg W3^T), bf16 out ----------------
// 128x64 tile, 4 waves (2x2), wave tile 64x32, dual acc = 64 AGPR total.
// global_load_lds into linear LDS; XOR chunk swizzle applied to the GLOBAL source
// and to LDS reads (rule 21). XCD-bijective block swizzle for B-strip L2 reuse.
__global__ __launch_bounds__(256, 2) void gemm1_kernel(const unsigned short* __restrict__ Xg,
                                                       const unsigned short* __restrict__ Wb1,
                                                       const unsigned short* __restrict__ Wb3,
                                                       const int* __restrict__ M,
                                                       unsigned short* __restrict__ H) {
    __shared__ __align__(16) unsigned short As[TM * BK];    // 16 KB
    __shared__ __align__(16) unsigned short B1s[TN1 * BK];  // 8 KB
    __shared__ __align__(16) unsigned short B3s[TN1 * BK];  // 8 KB
    // XCD swizzle: HW block h -> logical (h%8)*(nwg/8) + h/8 ; nwg = NE*1280 (%8==0)
    int bx = (blockIdx.x & 7) * (NE * 1280 / 8) + (blockIdx.x >> 3);
    int e = bx / 1280;                // 1280 = 64 n-tiles * 20 m-tiles
    int r = bx - e * 1280;
    int nt = r / 20;                  // mt fastest: B-strips shared by consecutive blocks
    int mt = r - nt * 20;
    if (mt * TM >= M[e]) return;      // tile fully in zero-padded region: H never read there
    const unsigned short* Ab  = Xg  + ((size_t)e * RPE + (size_t)mt * TM) * D_MODEL;
    const unsigned short* B1b = Wb1 + (size_t)e * D_FF * D_MODEL + (size_t)nt * TN1 * D_MODEL;
    const unsigned short* B3b = Wb3 + (size_t)e * D_FF * D_MODEL + (size_t)nt * TN1 * D_MODEL;
    int tid = threadIdx.x;
    int lane = tid & 63, wv = tid >> 6;
    int wm = wv & 1, wn = wv >> 1;    // 2x2 wave grid
    int quad = lane >> 4, l16 = lane & 15;
    f4v acc1[4][2], acc3[4][2];
    #pragma unroll
    for (int i = 0; i < 4; i++)
        #pragma unroll
        for (int j = 0; j < 2; j++) { acc1[i][j] = 0.0f; acc3[i][j] = 0.0f; }

    for (int kt = 0; kt < D_MODEL / BK; kt++) {
        int kof = kt * BK;
        __syncthreads();              // previous iter's LDS reads done before overwrite
        #pragma unroll
        for (int c = 0; c < 4; c++) { // A tile: 128 rows x 8 chunks = 1024 chunks
            int chunk = c * 256 + tid;
            int row = chunk >> 3;
            int ch  = chunk & 7;
            int gcol = (ch ^ (row & 7)) * 8;          // inverse swizzle on global src
            int lb = (c * 256 + wv * 64) * 8;         // wave-uniform LDS elem base
            gload16(Ab + (size_t)row * D_MODEL + kof + gcol, As + lb);
        }
        #pragma unroll
        for (int c = 0; c < 2; c++) { // B tiles: 64 rows x 8 chunks = 512 chunks each
            int chunk = c * 256 + tid;
            int row = chunk >> 3;
            int ch  = chunk & 7;
            int gcol = (ch ^ (row & 7)) * 8;
            int lb = (c * 256 + wv * 64) * 8;
            gload16(B1b + (size_t)row * D_MODEL + kof + gcol, B1s + lb);
            gload16(B3b + (size_t)row * D_MODEL + kof + gcol, B3s + lb);
        }
        __syncthreads();              // vmcnt(0) drain: staged tile visible
        #pragma unroll
        for (int st = 0; st < 2; st++) {
            s8v af[4], bf1[2], bf3[2];
            int cbase = st * 32 + quad * 8;           // element col, multiple of 8
            #pragma unroll
            for (int i = 0; i < 4; i++) {
                int row = wm * 64 + i * 16 + l16;
                af[i] = *(const s8v*)(As + row * BK + (cbase ^ ((row & 7) << 3)));
            }
            #pragma unroll
            for (int j = 0; j < 2; j++) {
                int row = wn * 32 + j * 16 + l16;
                bf1[j] = *(const s8v*)(B1s + row * BK + (cbase ^ ((row & 7) << 3)));
                bf3[j] = *(const s8v*)(B3s + row * BK + (cbase ^ ((row & 7) << 3)));
            }
            #pragma unroll
            for (int i = 0; i < 4; i++)
                #pragma unroll
                for (int j = 0; j < 2; j++) {
                    acc1[i][j] = __builtin_amdgcn_mfma_f32_16x16x32_bf16(af[i], bf1[j], acc1[i][j], 0, 0, 0);
                    acc3[i][j] = __builtin_amdgcn_mfma_f32_16x16x32_bf16(af[i], bf3[j], acc3[i][j], 0, 0, 0);
                }
        }
    }
    size_t rowbase = (size_t)e * RPE + (size_t)mt * TM;
    #pragma unroll
    for (int i = 0; i < 4; i++) {
        #pragma unroll
        for (int j = 0; j < 2; j++) {
            int col = nt * TN1 + wn * 32 + j * 16 + l16;
            #pragma unroll
            for (int rg = 0; rg < 4; rg++) {
                int row = wm * 64 + i * 16 + quad * 4 + rg;   // C/D: col=lane&15, row=quad*4+reg
                float z = acc1[i][j][rg];
                float sg = z / (1.0f + __expf(-z));           // silu
                float h = sg * acc3[i][j][rg];
                H[(rowbase + row) * (size_t)D_FF + col] = f2bf(h);
            }
        }
    }
}

// ---------------- GEMM2: O = H W2^T (raw expert rows, NO atomics) ----------------
__global__ __launch_bounds__(256, 2) void gemm2_kernel(const unsigned short* __restrict__ H,
                                                       const unsigned short* __restrict__ Wb2,
                                                       const int* __restrict__ M,
                                                       float* __restrict__ O) {
    __shared__ __align__(16) unsigned short As[TM * BK];
    __shared__ __align__(16) unsigned short Bs[TN * BK];
    // XCD swizzle: nwg = NE*160 = 1280 (%8==0)
    int bx = (blockIdx.x & 7) * (NE * 160 / 8) + (blockIdx.x >> 3);
    int e = bx / 160;                 // 160 = 20 m-tiles * 8 n-tiles
    int r = bx - e * 160;
    int mt = r >> 3;                  // nt fastest: A-tile shared by consecutive blocks
    int nt = r & 7;
    if (mt * TM >= M[e]) return;      // masked rows only: skip whole tile
    const unsigned short* Ab = H + ((size_t)e * RPE + (size_t)mt * TM) * D_FF;
    const unsigned short* Bb = Wb2 + (size_t)e * D_MODEL * D_FF + (size_t)nt * TN * D_FF;
    int tid = threadIdx.x;
    int lane = tid & 63, wv = tid >> 6;
    int wm = wv & 1, wn = wv >> 1;
    int quad = lane >> 4, l16 = lane & 15;
    f4v acc[4][4];
    #pragma unroll
    for (int i = 0; i < 4; i++)
        #pragma unroll
        for (int j = 0; j < 4; j++) acc[i][j] = 0.0f;

    for (int kt = 0; kt < D_FF / BK; kt++) {
        int kof = kt * BK;
        __syncthreads();
        #pragma unroll
        for (int c = 0; c < 4; c++) {
            int chunk = c * 256 + tid;
            int row = chunk >> 3;
            int ch  = chunk & 7;
            int gcol = (ch ^ (row & 7)) * 8;
            int lb = (c * 256 + wv * 64) * 8;
            gload16(Ab + (size_t)row * D_FF + kof + gcol, As + lb);
            gload16(Bb + (size_t)row * D_FF + kof + gcol, Bs + lb);
        }
        __syncthreads();
        #pragma unroll
        for (int st = 0; st < 2; st++) {
            s8v af[4], bf[4];
            int cbase = st * 32 + quad * 8;
            #pragma unroll
            for (int i = 0; i < 4; i++) {
                int row = wm * 64 + i * 16 + l16;
                af[i] = *(const s8v*)(As + row * BK + (cbase ^ ((row & 7) << 3)));
            }
            #pragma unroll
            for (int j = 0; j < 4; j++) {
                int row = wn * 64 + j * 16 + l16;
                bf[j] = *(const s8v*)(Bs + row * BK + (cbase ^ ((row & 7) << 3)));
            }
            #pragma unroll
            for (int i = 0; i < 4; i++)
                #pragma unroll
                for (int j = 0; j < 4; j++)
                    acc[i][j] = __builtin_amdgcn_mfma_f32_16x16x32_bf16(af[i], bf[j], acc[i][j], 0, 0, 0);
        }
    }
    size_t rowbase = (size_t)e * RPE + (size_t)mt * TM;
    #pragma unroll
    for (int i = 0; i < 4; i++) {
        #pragma unroll
        for (int j = 0; j < 4; j++) {
            int col = nt * TN + wn * 64 + j * 16 + l16;
            #pragma unroll
            for (int rg = 0; rg < 4; rg++) {
                int row = wm * 64 + i * 16 + quad * 4 + rg;
                // rows >= M[e] inside a live tile: H rows are 0 there -> O=0, never read
                O[(rowbase + row) * (size_t)D_MODEL + col] = acc[i][j][rg];
            }
        }
    }
}

// ---------------- combine: out[t] = w0*O[r0] + w1*O[r1] (plain stores) ----------------
__global__ __launch_bounds__(256) void combine_kernel(const float* __restrict__ O,
                                                      const int* __restrict__ inv0,
                                                      const int* __restrict__ inv1,
                                                      const float* __restrict__ w0a,
                                                      const float* __restrict__ w1a,
                                                      float* __restrict__ out) {
    int wv = threadIdx.x >> 6, lane = threadIdx.x & 63;
    int t = blockIdx.x * 4 + wv;
    int r0 = inv0[t], r1 = inv1[t];
    float w0 = w0a[t], w1 = w1a[t];
    const float4* O0 = (const float4*)(O + (size_t)(r0 < 0 ? 0 : r0) * D_MODEL);
    const float4* O1 = (const float4*)(O + (size_t)(r1 < 0 ? 0 : r1) * D_MODEL);
    float4* dst = (float4*)(out + (size_t)t * D_MODEL);
    float4 z; z.x = z.y = z.z = z.w = 0.0f;
    #pragma unroll
    for (int j = 0; j < 4; j++) {
        int d = lane + 64 * j;
        float4 a = (r0 >= 0) ? O0[d] : z;   // wave-uniform branch; avoids NaN*0 from garbage
        float4 b = (r1 >= 0) ? O1[d] : z;
        float4 rr;
        rr.x = w0 * a.x + w1 * b.x;
        rr.y = w0 * a.y + w1 * b.y;
        rr.z = w0 * a.z + w1 * b.z;
        rr.w = w0 * a.w + w1 * b.w;
        dst[d] = rr;
    }
}

// ---------------- aux loss finisher: reduce per-block prob partials ----------------
__global__ __launch_bounds__(64) void aux_kernel(const int* __restrict__ counts,
                                                 const float* __restrict__ partial,
                                                 float* __restrict__ out_aux) {
    __shared__ float red[64];
    int tid = threadIdx.x;
    int e = tid & 7;            // expert
    int chunk = tid >> 3;       // 8 chunks of 256 blocks
    float s = 0.0f;
    for (int b = chunk * (RBLK / 8); b < (chunk + 1) * (RBLK / 8); b++)
        s += partial[b * NE + e];
    red[tid] = s;
    __syncthreads();
    if (tid == 0) {
        float total = 0.0f;
        for (int e2 = 0; e2 < NE; e2++) {
            float P = 0.0f;
            for (int c = 0; c < 8; c++) P += red[c * 8 + e2];
            P /= (float)NTOK;
            float f = (float)counts[e2] / (float)(NTOK * 2);
            total += f * P;
        }
        *out_aux = (float)NE * total;
    }
}

extern "C" void kernel_launch(void* const* d_in, const int* in_sizes, int n_in,
                              void* d_out, int out_size, void* d_ws, size_t ws_size,
                              hipStream_t stream) {
    (void)in_sizes; (void)n_in; (void)ws_size; (void)out_size;
    const float* x    = (const float*)d_in[0];
    const float* gate = (const float*)d_in[1];
    const float* w1   = (const float*)d_in[2];
    const float* w2   = (const float*)d_in[3];   // dict order: x, gate_w, w1, w2, w3
    const float* w3   = (const float*)d_in[4];
    float* out = (float*)d_out;

    const size_t WB = (size_t)NE * D_FF * D_MODEL * 2;   // 64 MB per weight in bf16
    char* p = (char*)d_ws;
    unsigned short* Wb1 = (unsigned short*)p;  p += WB;
    unsigned short* Wb3 = (unsigned short*)p;  p += WB;
    unsigned short* Wb2 = (unsigned short*)p;  p += WB;
    unsigned short* Xg  = (unsigned short*)p;  p += (size_t)RTOT * D_MODEL * 2;
    unsigned short* H   = (unsigned short*)p;  p += (size_t)RTOT * D_FF * 2;
    int*   e0a = (int*)p;    p += NTOK * 4;
    int*   e1a = (int*)p;    p += NTOK * 4;
    float* w0a = (float*)p;  p += NTOK * 4;
    float* w1a = (float*)p;  p += NTOK * 4;
    int*   tok = (int*)p;    p += RTOT * 4;
    int*   inv0 = (int*)p;   p += NTOK * 4;
    int*   inv1 = (int*)p;   p += NTOK * 4;
    int*   M   = (int*)p;    p += 64;
    int*   counts = (int*)p; p += 64;
    float* partial = (float*)p; p += RBLK * NE * 4;   // 2048*8 floats

    // O (20480 x 1024 fp32 = 80 MB) aliases Wb1+Wb3 (128 MB): weights W1/W3 are
    // dead after gemm1, stream is sequential -> safe reuse, no workspace growth.
    float* O = (float*)Wb1;

    int n4 = NE * D_FF * D_MODEL / 4;
    cvt_kernel<<<2048, 256, 0, stream>>>(w1, Wb1, n4);
    cvt_kernel<<<2048, 256, 0, stream>>>(w3, Wb3, n4);
    cvt_kernel<<<2048, 256, 0, stream>>>(w2, Wb2, n4);

    router_kernel<<<RBLK, 256, 0, stream>>>(x, gate, e0a, e1a, w0a, w1a, partial);
    scan_kernel<<<1, 512, 0, stream>>>(e0a, e1a, tok, inv0, inv1, M, counts);
    gather_kernel<<<RTOT / 4, 256, 0, stream>>>(x, tok, M, Xg);

    gemm1_kernel<<<NE * 20 * 64, 256, 0, stream>>>(Xg, Wb1, Wb3, M, H);
    gemm2_kernel<<<NE * 20 * 8, 256, 0, stream>>>(H, Wb2, M, O);

    combine_kernel<<<NTOK / 4, 256, 0, stream>>>(O, inv0, inv1, w0a, w1a, out);
    aux_kernel<<<1, 64, 0, stream>>>(counts, partial, out + (size_t)NTOK * D_MODEL);
}